// Round 3
// baseline (12478.458 us; speedup 1.0000x reference)
//
#include <hip/hip_runtime.h>
#include <stdint.h>

// Problem constants (match reference)
#define B 128
#define S 256
#define T 256
#define EMBED 256
#define ENC 256
#define DEC 512
#define DOF 4

typedef __attribute__((ext_vector_type(8))) short bf16x8;   // 8 bf16 = 4 VGPRs (MFMA A/B frag)
typedef __attribute__((ext_vector_type(4))) float f32x4;    // MFMA C/D frag

static __device__ __forceinline__ float bf2f(unsigned short u){
  union{uint32_t u;float f;}c; c.u = ((uint32_t)u)<<16; return c.f;
}
static __device__ __forceinline__ unsigned short f2bf(float f){
  union{float f;uint32_t u;}c; c.f=f; uint32_t u=c.u;
  u += 0x7fffu + ((u>>16)&1u);  // round-to-nearest-even
  return (unsigned short)(u>>16);
}
static __device__ __forceinline__ void unp2(uint32_t w, float&a, float&b){
  union{uint32_t u;float f;}c1,c2; c1.u = w<<16; c2.u = w & 0xffff0000u; a=c1.f; b=c2.f;
}
static __device__ __forceinline__ float sigm(float x){ return 1.0f/(1.0f+__expf(-x)); }

// ---------------------------------------------------------------------------
// Coherent (agent-scope, cache-bypassing) accessors for cross-block state.
// Read-only data (weights, encOut, proj, win, emb) uses NORMAL cached loads.
// ---------------------------------------------------------------------------
static __device__ __forceinline__ unsigned long long ldc8(const void* p){
  return __hip_atomic_load((unsigned long long*)p, __ATOMIC_RELAXED, __HIP_MEMORY_SCOPE_AGENT);
}
static __device__ __forceinline__ void stc8(void* p, unsigned long long v){
  __hip_atomic_store((unsigned long long*)p, v, __ATOMIC_RELAXED, __HIP_MEMORY_SCOPE_AGENT);
}
union F16x8 { unsigned long long q[2]; bf16x8 v; unsigned short s[8]; };
union Ubf   { bf16x8 v; uint32_t u[4]; unsigned short s[8]; };
union F32x2 { unsigned long long q; float f[2]; };
union F32x8c{ unsigned long long q[4]; float f[8]; };
static __device__ __forceinline__ bf16x8 ldfrag_c(const unsigned short* p){
  F16x8 u; u.q[0] = ldc8(p); u.q[1] = ldc8(p + 4); return u.v;
}
static __device__ __forceinline__ unsigned long long pack4bf(float a,float b,float c,float d){
  return (unsigned long long)f2bf(a) | ((unsigned long long)f2bf(b)<<16)
       | ((unsigned long long)f2bf(c)<<32) | ((unsigned long long)f2bf(d)<<48);
}

// ---------------------------------------------------------------------------
// Spread-counter device barriers: 16 cache lines per barrier set; arrivals
// fetch_add their line; one wave polls all 16 lines (__all across 64 lanes).
// ---------------------------------------------------------------------------
#define CLINE 32   // u32 per counter line (128 B)
#define A_OFF 0
#define C_OFF 32
#define F_OFF 48
#define PAIR_OFF 64
#define ENC_OFF 192
static __device__ __forceinline__ unsigned* cl(unsigned* c, int line){ return c + (size_t)line*CLINE; }

static __device__ __forceinline__ void bar_arr(unsigned* line){
  __builtin_amdgcn_s_waitcnt(0);     // drain this wave's coherent stores
  __syncthreads();                   // all waves drained
  if (threadIdx.x == 0)
    __hip_atomic_fetch_add(line, 1u, __ATOMIC_RELAXED, __HIP_MEMORY_SCOPE_AGENT);
}
static __device__ __forceinline__ void barw(unsigned* set16, unsigned target){
  if (threadIdx.x < 64){
    unsigned* p = set16 + (size_t)(threadIdx.x & 15)*CLINE;
    while (!__all((int)(__hip_atomic_load(p, __ATOMIC_RELAXED, __HIP_MEMORY_SCOPE_AGENT) >= target)))
      __builtin_amdgcn_s_sleep(1);
  }
  __syncthreads();
  asm volatile("" ::: "memory");
}

// swizzled LDS offset (in shorts) for proj tile: row s, 16B-granule g (0..63)
static __device__ __forceinline__ int lds_off(int s, int g){
  return s*512 + (((g & 56) | ((g ^ s) & 7)) << 3);
}

// ---------------------------------------------------------------------------
// Persistent bi-LSTM encoder. Grid 256 = dir(2) x mg(2) x ng(64).
// ---------------------------------------------------------------------------
__global__ __launch_bounds__(256,1) void k_encoder(
  const unsigned short* __restrict__ emb,   // (S,B,256)
  const unsigned short* __restrict__ WF, const unsigned short* __restrict__ WB,
  const float* __restrict__ bF, const float* __restrict__ bB,
  unsigned short* __restrict__ hEnc,        // [dir][2][B][256]
  unsigned short* __restrict__ encOut,      // [B][S][512]
  unsigned* __restrict__ cntBase)           // 2 sets of 16 lines
{
  __shared__ __align__(16) unsigned short Ws[16*520];
  __shared__ __align__(16) float Gs[64*17];
  __shared__ float bsh[16];
  const int bid = blockIdx.x;
  const int dir = bid >> 7;
  const int mg  = (bid >> 6) & 1;
  const int ng  = bid & 63;
  const int tid = threadIdx.x;
  const int lane = tid & 63, w = tid >> 6;
  const int l16 = lane & 15, qd = lane >> 4;
  const int m_base = mg * 64;
  unsigned* mycnt = cntBase + (size_t)dir*16*CLINE;
  unsigned* myline = cl(mycnt, bid & 15);

  const unsigned short* Wg = (dir ? WB : WF) + (size_t)ng*16*512;
  for (int i = tid; i < 16*64; i += 256){
    const int r = i >> 6, s = i & 63;
    *(uint4*)&Ws[r*520 + s*8] = *(const uint4*)&Wg[r*512 + s*8];
  }
  if (tid < 16) bsh[tid] = (dir ? bB : bF)[ng*16 + tid];
  float c[4] = {0.f,0.f,0.f,0.f};
  __syncthreads();

  for (int t = 0; t < S; ++t){
    const int tt = dir ? (S-1-t) : t;
    const unsigned short* Ae = emb + ((size_t)tt*B + m_base + w*16 + l16)*256 + qd*8;
    bf16x8 av[8];
#pragma unroll
    for (int ks = 0; ks < 8; ++ks) av[ks] = *(const bf16x8*)(Ae + ks*32);   // prefetch (cached)
    if (t) barw(mycnt, (unsigned)(8u*(unsigned)t));
    const unsigned short* Ah = hEnc + (((size_t)dir*2 + (size_t)(t&1))*B + m_base + w*16 + l16)*256 + qd*8;
    bf16x8 hf[8];
#pragma unroll
    for (int ks = 0; ks < 8; ++ks) hf[ks] = ldfrag_c(Ah + ks*32);
    f32x4 acc = (f32x4){0.f,0.f,0.f,0.f};
#pragma unroll
    for (int ks = 0; ks < 8; ++ks){
      bf16x8 bb = *(const bf16x8*)&Ws[l16*520 + ks*32 + qd*8];
      acc = __builtin_amdgcn_mfma_f32_16x16x32_bf16(av[ks], bb, acc, 0, 0, 0);
    }
#pragma unroll
    for (int ks = 0; ks < 8; ++ks){
      bf16x8 bb = *(const bf16x8*)&Ws[l16*520 + 256 + ks*32 + qd*8];
      acc = __builtin_amdgcn_mfma_f32_16x16x32_bf16(hf[ks], bb, acc, 0, 0, 0);
    }
    __syncthreads();
#pragma unroll
    for (int r = 0; r < 4; ++r)
      Gs[(w*16 + qd*4 + r)*17 + l16] = acc[r];
    __syncthreads();
    if (tid < 64){
      const int bl = tid;
      float hv[4];
#pragma unroll
      for (int u = 0; u < 4; ++u){
        const float gi = Gs[bl*17 + u*4 + 0] + bsh[u*4 + 0];
        const float gf = Gs[bl*17 + u*4 + 1] + bsh[u*4 + 1];
        const float gg = Gs[bl*17 + u*4 + 2] + bsh[u*4 + 2];
        const float go = Gs[bl*17 + u*4 + 3] + bsh[u*4 + 3];
        const float cn = sigm(gf)*c[u] + sigm(gi)*tanhf(gg);
        c[u] = cn;
        hv[u] = sigm(go)*tanhf(cn);
      }
      const int b2 = m_base + bl;
      const unsigned long long hq = pack4bf(hv[0],hv[1],hv[2],hv[3]);
      stc8(&hEnc[(((size_t)dir*2 + (size_t)((t+1)&1))*B + b2)*256 + ng*4], hq);
      *(unsigned long long*)&encOut[((size_t)b2*S + tt)*512 + dir*256 + ng*4] = hq;
    }
    bar_arr(myline);
  }
}

// ---------------------------------------------------------------------------
// proj = encOut @ W_src^T, precomputed once (step-invariant, as in reference).
// Output layout (B, 2, 128, 512): s-half-major so decoder block (b,sh) loads
// its 128x512 tile (128 KB) contiguously.
// ---------------------------------------------------------------------------
__global__ __launch_bounds__(256,2) void k_proj(
  const unsigned short* __restrict__ encOut,  // (B*S, 512)
  const unsigned short* __restrict__ WSP,     // swizzled B-frags (n=d, k=e)
  unsigned short* __restrict__ proj)          // (B, 2, 128, 512)
{
  const int nb = blockIdx.x & 7;
  const int mt = blockIdx.x >> 3;
  const int tid = threadIdx.x;
  const int lane = tid & 63, w = tid >> 6;
  const int l16 = lane & 15, qd = lane >> 4;
  const int m0 = mt*64 + w*16;
  const unsigned short* Ap = encOut + ((size_t)m0 + l16)*512 + qd*8;
  bf16x8 av[16];
#pragma unroll
  for (int ks = 0; ks < 16; ++ks) av[ks] = *(const bf16x8*)(Ap + ks*32);
  for (int nn = 0; nn < 4; ++nn){
    const int qn = nb*4 + nn;          // 16-wide d group
    const unsigned short* Bq = WSP + (size_t)qn*16*512 + (size_t)lane*8;
    f32x4 acc = (f32x4){0.f,0.f,0.f,0.f};
#pragma unroll
    for (int ks = 0; ks < 16; ++ks){
      bf16x8 bb = *(const bf16x8*)(Bq + (size_t)ks*512);
      acc = __builtin_amdgcn_mfma_f32_16x16x32_bf16(av[ks], bb, acc, 0, 0, 0);
    }
    const int d = qn*16 + l16;
#pragma unroll
    for (int r = 0; r < 4; ++r){
      const int m = m0 + qd*4 + r;
      const int bb2 = m >> 8, s = m & 255;
      proj[(((size_t)bb2*2 + (s >> 7))*128 + (s & 127))*512 + d] = f2bf(acc[r]);
    }
  }
}

// ---------------------------------------------------------------------------
// Persistent decoder. Grid 256; block i owns (batch b=i>>1, s-half sh=i&1),
// holds proj[b, sh-half, ALL 512 d] in LDS (128 KB) for all steps.
// Scores are computed FULLY locally (no cross-block partial-score hop);
// softmax decomposed flash-style across the two s-halves:
//   each half -> local (m,l), unnormalized e, f32 partial ctx;
//   feed blocks combine halves inline while building A-frags;
//   aw finalize (needs peer m,l) is OFF-CHAIN.
// Chain per step: Fwait -> gates -> barA -> scores+exp+partial-ctx -> barC
//                 -> feed (combine inline) -> barF.   (3 hops)
// ---------------------------------------------------------------------------
__global__ __launch_bounds__(256,1) void k_decoder(
  const unsigned short* __restrict__ win,    // (T,B,64)
  const unsigned short* __restrict__ WDx,    // swizzled gates weights
  const float* __restrict__ bD,              // 2048 reordered
  const unsigned short* __restrict__ WCx,    // swizzled W_ctx
  const unsigned short* __restrict__ projq,  // (B,2,128,512) precomputed proj
  const unsigned short* __restrict__ encOut, // (B,S,512)
  const int* __restrict__ in_seq,
  const float* __restrict__ Wout, const float* __restrict__ bout,
  unsigned short* __restrict__ hdec,         // [2][B][512]
  unsigned short* __restrict__ feed,         // [B][512]
  float* __restrict__ ctxp,                  // [B][2][512] f32 partial ctx
  float* __restrict__ mlp,                   // [B][2][2] f32 (m,l)
  float* __restrict__ out_main, float* __restrict__ out_attn,
  unsigned* __restrict__ cnts)
{
  __shared__ __align__(16) unsigned short encS[65536];  // 128 KB resident proj tile
  __shared__ __align__(16) float scrf[3296];
  __shared__ float bsh[16];
  const int bid = blockIdx.x;
  const int b  = bid >> 1, sh = bid & 1;
  const int mg = bid & 1, ng = (bid >> 1) & 127;
  const int tid = threadIdx.x;
  const int lane = tid & 63, w = tid >> 6;
  const int l16 = lane & 15, qd = lane >> 4;
  const int m_base = mg*64;
  const int r = tid >> 1;                 // attention row within this s-half

  // ---- init: bias, mask, resident proj tile (swizzled) ----
  if (tid < 16) bsh[tid] = bD[ng*16 + tid];
  const int mymask = (in_seq[b*S + sh*128 + r] == 0);
  {
    const unsigned short* Pq = projq + (((size_t)b*2 + sh)*128)*512;
    for (int i = 0; i < 32; ++i){
      const int gid = i*256 + tid;        // 0..8191
      const int s = gid >> 6, g = gid & 63;
      const uint4 v = *(const uint4*)&Pq[(size_t)s*512 + g*8];
      *(uint4*)&encS[lds_off(s, g)] = v;
    }
  }
  float c[4] = {0.f,0.f,0.f,0.f};
  __syncthreads();

  for (int t = 0; t < T; ++t){
    // ---------------- phase A: gates + LSTM update ----------------
    const int row = m_base + w*16 + l16;
    const unsigned short* Aw = win  + ((size_t)t*B + row)*64 + qd*8;
    const unsigned short* Af = feed + (size_t)row*512 + qd*8;
    const unsigned short* Ah = hdec + ((size_t)(t&1)*B + row)*512 + qd*8;
    const unsigned short* Bp = WDx + (size_t)ng*34*512 + (size_t)lane*8;
    f32x4 acc = (f32x4){0.f,0.f,0.f,0.f};
    // pre-wait: h-part of gates (h_{t-1} visible since prev barA) — off chain
    {
      bf16x8 hv[16];
#pragma unroll
      for (int i = 0; i < 16; ++i) hv[i] = ldfrag_c(Ah + i*32);
#pragma unroll
      for (int ks = 0; ks < 16; ++ks){
        bf16x8 bb = *(const bf16x8*)(Bp + (size_t)(18+ks)*512);
        acc = __builtin_amdgcn_mfma_f32_16x16x32_bf16(hv[ks], bb, acc, 0, 0, 0);
      }
    }
    // prefetch feed-part weights + win frags (cached) before the wait
    bf16x8 bv0[18];
#pragma unroll
    for (int ks = 0; ks < 18; ++ks) bv0[ks] = *(const bf16x8*)(Bp + (size_t)ks*512);
    bf16x8 a0 = *(const bf16x8*)(Aw);
    bf16x8 a1 = *(const bf16x8*)(Aw + 32);
    if (t) barw(cl(cnts, F_OFF), (unsigned)(4u*(unsigned)t));   // feed_{t-1} ready
    {
      bf16x8 av[18];
      av[0] = a0; av[1] = a1;
#pragma unroll
      for (int i = 0; i < 16; ++i) av[2+i] = ldfrag_c(Af + i*32);
#pragma unroll
      for (int ks = 0; ks < 18; ++ks)
        acc = __builtin_amdgcn_mfma_f32_16x16x32_bf16(av[ks], bv0[ks], acc, 0, 0, 0);
    }
    __syncthreads();
#pragma unroll
    for (int rr = 0; rr < 4; ++rr)
      scrf[(w*16 + qd*4 + rr)*17 + l16] = acc[rr];
    __syncthreads();
    if (tid < 64){
      float hv[4];
#pragma unroll
      for (int u = 0; u < 4; ++u){
        const float gi = scrf[tid*17 + u*4 + 0] + bsh[u*4 + 0];
        const float gf = scrf[tid*17 + u*4 + 1] + bsh[u*4 + 1];
        const float gg = scrf[tid*17 + u*4 + 2] + bsh[u*4 + 2];
        const float go = scrf[tid*17 + u*4 + 3] + bsh[u*4 + 3];
        const float cn = sigm(gf)*c[u] + sigm(gi)*tanhf(gg);
        c[u] = cn;
        hv[u] = sigm(go)*tanhf(cn);
      }
      stc8(&hdec[((size_t)((t+1)&1)*B + m_base + tid)*512 + ng*4],
           pack4bf(hv[0],hv[1],hv[2],hv[3]));
    }
    bar_arr(cl(cnts, A_OFF + (bid & 15)));

    // out-projection of feed_{t-1} (odd blocks; overlaps barA stragglers)
    if ((bid & 1) && t > 0){
      const int b2o = bid >> 1;
      const int d = tid >> 6, kk = lane;
      const unsigned short* fp = feed + (size_t)b2o*512 + kk*8;
      F16x8 u; u.q[0] = ldc8(fp); u.q[1] = ldc8(fp + 4);
      const float* wp = Wout + d*512 + kk*8;
      float p = 0.f;
#pragma unroll
      for (int j2 = 0; j2 < 8; ++j2) p += bf2f(u.s[j2]) * wp[j2];
#pragma unroll
      for (int off = 32; off > 0; off >>= 1) p += __shfl_down(p, off, 64);
      if (kk == 0){
        const float v = p + bout[d];
        out_main[((size_t)b2o*T + (t-1))*4 + d] = (d < 3) ? tanhf(v) : fmaxf(v, 0.f);
      }
    }

    // ---------------- attention (block computes FULL scores for its s-half) ----
    barw(cl(cnts, A_OFF), (unsigned)(16u*(unsigned)(t+1)));   // full h_t visible
    if (tid < 64){   // h[b, 0..512] -> scrf[0..511] floats
      F16x8 uh; const unsigned short* hp = hdec + ((size_t)((t+1)&1)*B + b)*512 + tid*8;
      uh.q[0] = ldc8(hp); uh.q[1] = ldc8(hp + 4);
#pragma unroll
      for (int j = 0; j < 8; ++j) scrf[tid*8 + j] = bf2f(uh.s[j]);
    }
    __syncthreads();
    float sc = 0.f;
    {
      const int dh = tid & 1;
#pragma unroll 8
      for (int cix = 0; cix < 32; ++cix){
        const int g = dh*32 + cix;
        Ubf u8; u8.v = *(const bf16x8*)&encS[lds_off(r, g)];
        float f0,f1,f2,f3,f4,f5,f6,f7;
        unp2(u8.u[0],f0,f1); unp2(u8.u[1],f2,f3); unp2(u8.u[2],f4,f5); unp2(u8.u[3],f6,f7);
        const float* qp = &scrf[dh*256 + cix*8];
        sc += f0*qp[0] + f1*qp[1] + f2*qp[2] + f3*qp[3]
            + f4*qp[4] + f5*qp[5] + f6*qp[6] + f7*qp[7];
      }
    }
    sc += __shfl_xor(sc, 1, 64);          // both lanes of a row get the full dot
    if (mymask) sc = -1e30f;
    // local max over 128 rows
    float mx = sc;
#pragma unroll
    for (int off = 32; off > 0; off >>= 1) mx = fmaxf(mx, __shfl_xor(mx, off, 64));
    if (lane == 0) scrf[1100 + w] = mx;
    __syncthreads();
    mx = fmaxf(fmaxf(scrf[1100], scrf[1101]), fmaxf(scrf[1102], scrf[1103]));
    const float ee = __expf(sc - mx);
    if (!(tid & 1)) scrf[1120 + r] = ee;
    float lsum = (tid & 1) ? 0.f : ee;
#pragma unroll
    for (int off = 32; off > 0; off >>= 1) lsum += __shfl_xor(lsum, off, 64);
    if (lane == 0) scrf[1104 + w] = lsum;
    __syncthreads();
    lsum = scrf[1104] + scrf[1105] + scrf[1106] + scrf[1107];
    if (tid == 0){
      F32x2 u; u.f[0] = mx; u.f[1] = lsum;
      stc8(&mlp[((size_t)b*2 + sh)*2], u.q);
    }
    // partial ctx (f32): wave w covers rows w*32..w*32+31, lane owns 8-e chunk
    {
      float a[8] = {0,0,0,0,0,0,0,0};
      const unsigned short* Ep = encOut + ((size_t)(b*S + sh*128 + w*32))*512 + lane*8;
#pragma unroll 8
      for (int i2 = 0; i2 < 32; ++i2){
        const float wgt = scrf[1120 + w*32 + i2];
        Ubf u8; u8.v = *(const bf16x8*)(Ep + (size_t)i2*512);
        float f0,f1,f2,f3,f4,f5,f6,f7;
        unp2(u8.u[0],f0,f1); unp2(u8.u[1],f2,f3); unp2(u8.u[2],f4,f5); unp2(u8.u[3],f6,f7);
        a[0]+=wgt*f0; a[1]+=wgt*f1; a[2]+=wgt*f2; a[3]+=wgt*f3;
        a[4]+=wgt*f4; a[5]+=wgt*f5; a[6]+=wgt*f6; a[7]+=wgt*f7;
      }
#pragma unroll
      for (int j2 = 0; j2 < 8; ++j2) scrf[1248 + w*512 + lane*8 + j2] = a[j2];
    }
    __syncthreads();
    {
      const int e2 = tid*2;
      const float s0 = scrf[1248+e2]   + scrf[1248+512+e2]   + scrf[1248+1024+e2]   + scrf[1248+1536+e2];
      const float s1 = scrf[1248+e2+1] + scrf[1248+512+e2+1] + scrf[1248+1024+e2+1] + scrf[1248+1536+e2+1];
      F32x2 u; u.f[0] = s0; u.f[1] = s1;
      stc8(&ctxp[((size_t)b*2 + sh)*512 + e2], u.q);
    }
    bar_arr(cl(cnts, C_OFF + (bid & 15)));
    if (tid == 0)
      __hip_atomic_fetch_add(cl(cnts, PAIR_OFF + b), 1u, __ATOMIC_RELAXED, __HIP_MEMORY_SCOPE_AGENT);

    if ((bid & 3) == 3){
      // ------- phase F: feed = tanh([h|ctx] @ W_ctx^T), ctx combined inline ----
      const int fblk = bid >> 2, fm = fblk >> 5, fn = fblk & 31;
      const int frow = fm*64 + w*16 + l16;
      const unsigned short* Fh = hdec + ((size_t)((t+1)&1)*B + frow)*512 + qd*8;
      const unsigned short* Bf = WCx + (size_t)fn*32*512 + (size_t)lane*8;
      f32x4 fa = (f32x4){0.f,0.f,0.f,0.f};
      {   // h-part before ctx-wait (h ready since barA this step)
        bf16x8 av[16];
#pragma unroll
        for (int ks = 0; ks < 16; ++ks) av[ks] = ldfrag_c(Fh + ks*32);
#pragma unroll
        for (int ks = 0; ks < 16; ++ks){
          bf16x8 bb = *(const bf16x8*)(Bf + (size_t)ks*512);
          fa = __builtin_amdgcn_mfma_f32_16x16x32_bf16(av[ks], bb, fa, 0, 0, 0);
        }
      }
      bf16x8 bv2[16];
#pragma unroll
      for (int ks = 0; ks < 16; ++ks) bv2[ks] = *(const bf16x8*)(Bf + (size_t)(16+ks)*512);
      barw(cl(cnts, C_OFF), (unsigned)(16u*(unsigned)(t+1)));
      // per-row combine weights from both halves' (m,l)
      F32x2 u0, u1;
      u0.q = ldc8(&mlp[((size_t)frow*2 + 0)*2]);
      u1.q = ldc8(&mlp[((size_t)frow*2 + 1)*2]);
      const float M  = fmaxf(u0.f[0], u1.f[0]);
      const float a0 = __expf(u0.f[0] - M), a1 = __expf(u1.f[0] - M);
      const float Lr = u0.f[1]*a0 + u1.f[1]*a1;
      const float w0 = a0/Lr, w1 = a1/Lr;
#pragma unroll
      for (int ks = 0; ks < 16; ++ks){
        const int kk = ks*32 + qd*8;
        const float* p0 = &ctxp[((size_t)frow*2 + 0)*512 + kk];
        const float* p1 = &ctxp[((size_t)frow*2 + 1)*512 + kk];
        F32x8c c0, c1;
        c0.q[0]=ldc8(p0); c0.q[1]=ldc8(p0+2); c0.q[2]=ldc8(p0+4); c0.q[3]=ldc8(p0+6);
        c1.q[0]=ldc8(p1); c1.q[1]=ldc8(p1+2); c1.q[2]=ldc8(p1+4); c1.q[3]=ldc8(p1+6);
        Ubf o;
#pragma unroll
        for (int j2 = 0; j2 < 8; ++j2) o.s[j2] = f2bf(w0*c0.f[j2] + w1*c1.f[j2]);
        fa = __builtin_amdgcn_mfma_f32_16x16x32_bf16(o.v, bv2[ks], fa, 0, 0, 0);
      }
      __syncthreads();
#pragma unroll
      for (int rr = 0; rr < 4; ++rr)
        scrf[(w*16 + qd*4 + rr)*17 + l16] = tanhf(fa[rr]);
      __syncthreads();
      if (tid < 64){
        const int fb = fm*64 + tid;
#pragma unroll
        for (int u = 0; u < 4; ++u)
          stc8(&feed[(size_t)fb*512 + fn*16 + u*4],
               pack4bf(scrf[tid*17+u*4+0], scrf[tid*17+u*4+1],
                       scrf[tid*17+u*4+2], scrf[tid*17+u*4+3]));
      }
      bar_arr(cl(cnts, F_OFF + ((bid >> 2) & 15)));
      // aw finalize (peer (m,l) visible: all blocks passed barC)
      {
        F32x2 up; up.q = ldc8(&mlp[((size_t)b*2 + (1-sh))*2]);
        const float M2 = fmaxf(mx, up.f[0]);
        const float L2 = lsum*__expf(mx - M2) + up.f[1]*__expf(up.f[0] - M2);
        const float scale = __expf(mx - M2)/L2;
        if (!(tid & 1))
          __builtin_nontemporal_store(scrf[1120 + r]*scale,
                                      &out_attn[((size_t)b*T + t)*S + sh*128 + r]);
      }
    } else {
      // non-feed blocks: wait only for the PEER's barC arrival, then finalize aw
      if (tid == 0){
        unsigned* pp = cl(cnts, PAIR_OFF + b);
        while (__hip_atomic_load(pp, __ATOMIC_RELAXED, __HIP_MEMORY_SCOPE_AGENT) < 2u*(unsigned)(t+1))
          __builtin_amdgcn_s_sleep(1);
      }
      __syncthreads();
      F32x2 up; up.q = ldc8(&mlp[((size_t)b*2 + (1-sh))*2]);
      const float M2 = fmaxf(mx, up.f[0]);
      const float L2 = lsum*__expf(mx - M2) + up.f[1]*__expf(up.f[0] - M2);
      const float scale = __expf(mx - M2)/L2;
      if (!(tid & 1))
        __builtin_nontemporal_store(scrf[1120 + r]*scale,
                                    &out_attn[((size_t)b*T + t)*S + sh*128 + r]);
    }
  }
  // final out-projection (feed_255)
  if (bid & 1){
    barw(cl(cnts, F_OFF), (unsigned)(4u*256u));
    const int b2o = bid >> 1;
    const int d = tid >> 6, kk = lane;
    const unsigned short* fp = feed + (size_t)b2o*512 + kk*8;
    F16x8 u; u.q[0] = ldc8(fp); u.q[1] = ldc8(fp + 4);
    const float* wp = Wout + d*512 + kk*8;
    float p = 0.f;
#pragma unroll
    for (int j2 = 0; j2 < 8; ++j2) p += bf2f(u.s[j2]) * wp[j2];
#pragma unroll
    for (int off = 32; off > 0; off >>= 1) p += __shfl_down(p, off, 64);
    if (kk == 0){
      const float v = p + bout[d];
      out_main[((size_t)b2o*T + 255)*4 + d] = (d < 3) ? tanhf(v) : fmaxf(v, 0.f);
    }
  }
}

// ---------------- setup / builder kernels ----------------
__global__ __launch_bounds__(256) void k_build_encw(
  const float* __restrict__ WihF, const float* __restrict__ WhhF,
  const float* __restrict__ WihB, const float* __restrict__ WhhB,
  unsigned short* WF, unsigned short* WB)
{
  const int idx = blockIdx.x*256 + threadIdx.x;     // 2*1024*512
  const int dir = idx >> 19;
  const int i2 = idx & 524287;
  const int row = i2 >> 9, col = i2 & 511;
  const int j = row >> 2, g = row & 3;
  const int orig = g*256 + j;
  const float* Wih = dir ? WihB : WihF;
  const float* Whh = dir ? WhhB : WhhF;
  const float v = (col < 256) ? Wih[orig*256 + col] : Whh[orig*256 + (col-256)];
  (dir ? WB : WF)[i2] = f2bf(v);
}

// gates weights: reorder rows (j*4+g), pad cols to 1088, swizzle to frag order
__global__ __launch_bounds__(256) void k_build_decw(
  const float* __restrict__ Wih, const float* __restrict__ Whh, unsigned short* WDx)
{
  const int idx = blockIdx.x*256 + threadIdx.x;
  if (idx >= 2048*1088) return;
  const int row = idx / 1088, col = idx - row*1088;
  const int j = row >> 2, g = row & 3;
  const int orig = g*512 + j;
  float v;
  if (col < 16)        v = Wih[orig*528 + col];          // w_t part
  else if (col < 64)   v = 0.f;                          // pad
  else if (col < 576)  v = Wih[orig*528 + (col - 48)];   // feed part
  else                 v = Whh[orig*512 + (col - 576)];  // h part
  const int ng = row >> 4, l16 = row & 15;
  const int ks = col >> 5, qdd = (col >> 3) & 3, jj = col & 7;
  WDx[(((size_t)ng*34 + ks)*64 + qdd*16 + l16)*8 + jj] = f2bf(v);
}

__global__ __launch_bounds__(256) void k_build_wcx(
  const float* __restrict__ Wctx, unsigned short* WCx)
{
  const int idx = blockIdx.x*256 + threadIdx.x;     // 512*1024
  const int n = idx >> 10, k = idx & 1023;
  const int fn = n >> 4, l16 = n & 15;
  const int ks = k >> 5, qdd = (k >> 3) & 3, jj = k & 7;
  WCx[(((size_t)fn*32 + ks)*64 + qdd*16 + l16)*8 + jj] = f2bf(Wctx[(size_t)n*1024 + k]);
}

// W_src in B-frag order for proj GEMM: n = d (512), k = e (512)
__global__ __launch_bounds__(256) void k_build_wsp(
  const float* __restrict__ Wsrc, unsigned short* WSP)
{
  const int idx = blockIdx.x*256 + threadIdx.x;     // 512*512
  const int d = idx >> 9, e = idx & 511;
  const int qn = d >> 4, l16 = d & 15;
  const int ks = e >> 5, qdd = (e >> 3) & 3, jj = e & 7;
  WSP[(((size_t)qn*16 + ks)*64 + qdd*16 + l16)*8 + jj] = f2bf(Wsrc[(size_t)d*512 + e]);
}

__global__ __launch_bounds__(256) void k_build_bias(
  const float* __restrict__ ebF, const float* __restrict__ ebB,
  const float* __restrict__ dB, float* bF, float* bB, float* bD)
{
  const int idx = blockIdx.x*256 + threadIdx.x;     // 4096
  if (idx < 1024) bF[idx] = ebF[(idx&3)*256 + (idx>>2)];
  else if (idx < 2048){ const int i = idx-1024; bB[i] = ebB[(i&3)*256 + (i>>2)]; }
  else { const int i = idx-2048; bD[i] = dB[(i&3)*512 + (i>>2)]; }
}

__global__ __launch_bounds__(256) void k_embed(
  const int* __restrict__ in_seq, const float* __restrict__ table, unsigned short* emb)
{
  const int idx = blockIdx.x*256 + threadIdx.x;     // S*B*256, layout (S,B,E)
  const int e = idx & 255, b = (idx >> 8) & 127, s = idx >> 15;
  const int tok = in_seq[b*S + s];
  emb[idx] = f2bf(table[(size_t)tok*256 + e]);
}

__global__ __launch_bounds__(256) void k_win(
  const float* __restrict__ tgt, unsigned short* win)
{
  const int idx = blockIdx.x*256 + threadIdx.x;     // T*B*64, layout (T,B,64)
  const int c = idx & 63, b = (idx >> 6) & 127, t = idx >> 13;
  float v = 0.f;
  if (c < 16){
    const int k = c >> 2, jj = c & 3;
    const int ts = t + k - 4;
    if (ts >= 0) v = tgt[((size_t)b*T + ts)*4 + jj];
  }
  win[idx] = f2bf(v);
}

// ---------------------------------------------------------------------------
extern "C" void kernel_launch(void* const* d_in, const int* in_sizes, int n_in,
                              void* d_out, int out_size, void* d_ws, size_t ws_size,
                              hipStream_t stream)
{
  const int*   in_seq    = (const int*)d_in[0];
  const float* tgt       = (const float*)d_in[1];
  // d_in[2] = lengths (unused by reference)
  const float* embedding = (const float*)d_in[3];
  const float* eWihF = (const float*)d_in[4];
  const float* eWhhF = (const float*)d_in[5];
  const float* ebF   = (const float*)d_in[6];
  const float* eWihB = (const float*)d_in[7];
  const float* eWhhB = (const float*)d_in[8];
  const float* ebB   = (const float*)d_in[9];
  const float* dWih  = (const float*)d_in[10];
  const float* dWhh  = (const float*)d_in[11];
  const float* dB    = (const float*)d_in[12];
  const float* Wsrc  = (const float*)d_in[13];
  const float* Wctx  = (const float*)d_in[14];
  const float* Wout  = (const float*)d_in[15];
  const float* bout  = (const float*)d_in[16];

  char* ws = (char*)d_ws;
  size_t off = 0;
  auto al = [&](size_t bytes)->char*{
    char* p = ws + off; off += (bytes + 255) & ~(size_t)255; return p; };

  // --- state region (zeroed every launch with one memset) ---
  char* stateBase = ws;
  unsigned short* hEnc = (unsigned short*)al(262144);  // [2][2][128][256]
  unsigned short* hdec = (unsigned short*)al(262144);  // [2][128][512]
  unsigned short* feed = (unsigned short*)al(131072);  // [128][512]
  unsigned*       cnts = (unsigned*)al(28672);         // 224 counter lines
  const size_t stateBytes = off;

  // --- persistent-per-launch scratch (fully rewritten each launch) ---
  unsigned short* emb    = (unsigned short*)al(16777216);  // (S,B,256) bf16
  unsigned short* win    = (unsigned short*)al(4194304);   // (T,B,64) bf16
  unsigned short* encOut = (unsigned short*)al(33554432);  // (B,S,512) bf16
  unsigned short* proj   = (unsigned short*)al(33554432);  // (B,2,128,512) bf16
  unsigned short* WF     = (unsigned short*)al(1048576);   // 1024x512
  unsigned short* WB     = (unsigned short*)al(1048576);
  unsigned short* WDx    = (unsigned short*)al(4456448);   // swizzled 2048x1088
  unsigned short* WCx    = (unsigned short*)al(1048576);   // swizzled 512x1024
  unsigned short* WSP    = (unsigned short*)al(524288);    // swizzled 512x512 (proj B)
  float*          ctxp   = (float*)al(524288);             // [128][2][512] f32
  float*          mlp    = (float*)al(2048);               // [128][2][2] f32
  float* bFr = (float*)al(4096);
  float* bBr = (float*)al(4096);
  float* bDr = (float*)al(8192);
  (void)ws_size; (void)in_sizes; (void)n_in; (void)out_size;

  float* out_main = (float*)d_out;
  float* out_attn = out_main + (size_t)B*T*DOF;

  const dim3 blk(256);
  k_build_encw <<<4096,  blk, 0, stream>>>(eWihF, eWhhF, eWihB, eWhhB, WF, WB);
  k_build_decw <<<8704,  blk, 0, stream>>>(dWih, dWhh, WDx);
  k_build_wcx  <<<2048,  blk, 0, stream>>>(Wctx, WCx);
  k_build_wsp  <<<1024,  blk, 0, stream>>>(Wsrc, WSP);
  k_build_bias <<<16,    blk, 0, stream>>>(ebF, ebB, dB, bFr, bBr, bDr);
  k_embed      <<<32768, blk, 0, stream>>>(in_seq, embedding, emb);
  k_win        <<<8192,  blk, 0, stream>>>(tgt, win);
  hipMemsetAsync(stateBase, 0, stateBytes, stream);

  // persistent encoder: 256 steps internally
  k_encoder<<<256, blk, 0, stream>>>(emb, WF, WB, bFr, bBr, hEnc, encOut,
                                     cnts + (size_t)ENC_OFF*CLINE);

  // one-shot proj GEMM (step-invariant attention projection)
  k_proj<<<4096, blk, 0, stream>>>(encOut, WSP, proj);

  // persistent decoder: 256 steps internally (proj LDS-resident, 3-hop chain)
  k_decoder<<<256, blk, 0, stream>>>(win, WDx, bDr, WCx, proj, encOut, in_seq,
                                     Wout, bout, hdec, feed, ctxp, mlp,
                                     out_main, out_attn, cnts);
}

// Round 4
// 10056.259 us; speedup vs baseline: 1.2409x; 1.2409x over previous
//
#include <hip/hip_runtime.h>
#include <stdint.h>

// Problem constants (match reference)
#define B 128
#define S 256
#define T 256
#define EMBED 256
#define ENC 256
#define DEC 512
#define DOF 4

typedef __attribute__((ext_vector_type(8))) short bf16x8;   // 8 bf16 = 4 VGPRs (MFMA A/B frag)
typedef __attribute__((ext_vector_type(4))) float f32x4;    // MFMA C/D frag

static __device__ __forceinline__ float bf2f(unsigned short u){
  union{uint32_t u;float f;}c; c.u = ((uint32_t)u)<<16; return c.f;
}
static __device__ __forceinline__ unsigned short f2bf(float f){
  union{float f;uint32_t u;}c; c.f=f; uint32_t u=c.u;
  u += 0x7fffu + ((u>>16)&1u);  // round-to-nearest-even
  return (unsigned short)(u>>16);
}
static __device__ __forceinline__ void unp2(uint32_t w, float&a, float&b){
  union{uint32_t u;float f;}c1,c2; c1.u = w<<16; c2.u = w & 0xffff0000u; a=c1.f; b=c2.f;
}
static __device__ __forceinline__ float sigm(float x){ return 1.0f/(1.0f+__expf(-x)); }

// ---------------------------------------------------------------------------
// Coherent (agent-scope, cache-bypassing) accessors for cross-block state.
// Read-only data (weights, encOut, proj, win, emb) uses NORMAL cached loads.
// ---------------------------------------------------------------------------
static __device__ __forceinline__ unsigned long long ldc8(const void* p){
  return __hip_atomic_load((unsigned long long*)p, __ATOMIC_RELAXED, __HIP_MEMORY_SCOPE_AGENT);
}
static __device__ __forceinline__ void stc8(void* p, unsigned long long v){
  __hip_atomic_store((unsigned long long*)p, v, __ATOMIC_RELAXED, __HIP_MEMORY_SCOPE_AGENT);
}
static __device__ __forceinline__ void stc4(void* p, unsigned v){
  __hip_atomic_store((unsigned*)p, v, __ATOMIC_RELAXED, __HIP_MEMORY_SCOPE_AGENT);
}
static __device__ __forceinline__ void stc4f(float* p, float v){
  __hip_atomic_store((unsigned*)p, __float_as_uint(v), __ATOMIC_RELAXED, __HIP_MEMORY_SCOPE_AGENT);
}
static __device__ __forceinline__ float ldc4f(const float* p){
  return __uint_as_float(__hip_atomic_load((const unsigned*)p, __ATOMIC_RELAXED, __HIP_MEMORY_SCOPE_AGENT));
}
union F16x8 { unsigned long long q[2]; bf16x8 v; unsigned short s[8]; };
union Ubf   { bf16x8 v; uint32_t u[4]; unsigned short s[8]; };
static __device__ __forceinline__ bf16x8 ldfrag_c(const unsigned short* p){
  F16x8 u; u.q[0] = ldc8(p); u.q[1] = ldc8(p + 4); return u.v;
}
static __device__ __forceinline__ unsigned long long pack4bf(float a,float b,float c,float d){
  return (unsigned long long)f2bf(a) | ((unsigned long long)f2bf(b)<<16)
       | ((unsigned long long)f2bf(c)<<32) | ((unsigned long long)f2bf(d)<<48);
}

// ---------------------------------------------------------------------------
// Spread-counter device barriers.
// A: 64 lines x 4 arrivals/step.  C: 64 lines x 4.  F: 64 lines x 1 (one line
// per feed block; fm=0 -> lines 0..31, fm=1 -> 32..63).  PAIR: 1 line/batch.
// Poller covers `mask+1` lines with one load per lane + __all.
// ---------------------------------------------------------------------------
#define CLINE 32   // u32 per counter line (128 B)
#define A_OFF 0
#define C_OFF 64
#define F_OFF 128
#define PAIR_OFF 192
#define ENC_OFF 320
static __device__ __forceinline__ unsigned* cl(unsigned* c, int line){ return c + (size_t)line*CLINE; }

static __device__ __forceinline__ void bar_arr(unsigned* line){
  __builtin_amdgcn_s_waitcnt(0);     // drain this wave's coherent stores
  __syncthreads();                   // all waves drained
  if (threadIdx.x == 0)
    __hip_atomic_fetch_add(line, 1u, __ATOMIC_RELAXED, __HIP_MEMORY_SCOPE_AGENT);
}
static __device__ __forceinline__ void barw(unsigned* set, unsigned target, int mask){
  if (threadIdx.x < 64){
    unsigned* p = set + (size_t)(threadIdx.x & mask)*CLINE;
    while (!__all((int)(__hip_atomic_load(p, __ATOMIC_RELAXED, __HIP_MEMORY_SCOPE_AGENT) >= target)))
      __builtin_amdgcn_s_sleep(1);
  }
  __syncthreads();
  asm volatile("" ::: "memory");
}
static __device__ __forceinline__ void pair_sync(unsigned* line, unsigned target){
  __builtin_amdgcn_s_waitcnt(0);
  __syncthreads();
  if (threadIdx.x == 0){
    __hip_atomic_fetch_add(line, 1u, __ATOMIC_RELAXED, __HIP_MEMORY_SCOPE_AGENT);
    while (__hip_atomic_load(line, __ATOMIC_RELAXED, __HIP_MEMORY_SCOPE_AGENT) < target)
      __builtin_amdgcn_s_sleep(1);
  }
  __syncthreads();
  asm volatile("" ::: "memory");
}

// swizzled LDS index (in shorts) for encS: row s (0..255), 16B-chunk c (0..31)
static __device__ __forceinline__ int enc_idx(int s, int c){
  return s*256 + (((c & 24) | ((c ^ s) & 7)) << 3);
}

// ---------------------------------------------------------------------------
// Persistent bi-LSTM encoder. Grid 256 = dir(2) x mg(2) x ng(64).
// ---------------------------------------------------------------------------
__global__ __launch_bounds__(256,1) void k_encoder(
  const unsigned short* __restrict__ emb,   // (S,B,256)
  const unsigned short* __restrict__ WF, const unsigned short* __restrict__ WB,
  const float* __restrict__ bF, const float* __restrict__ bB,
  unsigned short* __restrict__ hEnc,        // [dir][2][B][256]
  unsigned short* __restrict__ encOut,      // [B][S][512]
  unsigned* __restrict__ cntBase)           // 2 sets of 16 lines
{
  __shared__ __align__(16) unsigned short Ws[16*520];
  __shared__ __align__(16) float Gs[64*17];
  __shared__ float bsh[16];
  const int bid = blockIdx.x;
  const int dir = bid >> 7;
  const int mg  = (bid >> 6) & 1;
  const int ng  = bid & 63;
  const int tid = threadIdx.x;
  const int lane = tid & 63, w = tid >> 6;
  const int l16 = lane & 15, qd = lane >> 4;
  const int m_base = mg * 64;
  unsigned* mycnt = cntBase + (size_t)dir*16*CLINE;
  unsigned* myline = cl(mycnt, bid & 15);

  const unsigned short* Wg = (dir ? WB : WF) + (size_t)ng*16*512;
  for (int i = tid; i < 16*64; i += 256){
    const int r = i >> 6, s = i & 63;
    *(uint4*)&Ws[r*520 + s*8] = *(const uint4*)&Wg[r*512 + s*8];
  }
  if (tid < 16) bsh[tid] = (dir ? bB : bF)[ng*16 + tid];
  float c[4] = {0.f,0.f,0.f,0.f};
  __syncthreads();

  for (int t = 0; t < S; ++t){
    const int tt = dir ? (S-1-t) : t;
    const unsigned short* Ae = emb + ((size_t)tt*B + m_base + w*16 + l16)*256 + qd*8;
    bf16x8 av[8];
#pragma unroll
    for (int ks = 0; ks < 8; ++ks) av[ks] = *(const bf16x8*)(Ae + ks*32);   // prefetch (cached)
    if (t) barw(mycnt, (unsigned)(8u*(unsigned)t), 15);
    const unsigned short* Ah = hEnc + (((size_t)dir*2 + (size_t)(t&1))*B + m_base + w*16 + l16)*256 + qd*8;
    bf16x8 hf[8];
#pragma unroll
    for (int ks = 0; ks < 8; ++ks) hf[ks] = ldfrag_c(Ah + ks*32);
    f32x4 acc = (f32x4){0.f,0.f,0.f,0.f};
#pragma unroll
    for (int ks = 0; ks < 8; ++ks){
      bf16x8 bb = *(const bf16x8*)&Ws[l16*520 + ks*32 + qd*8];
      acc = __builtin_amdgcn_mfma_f32_16x16x32_bf16(av[ks], bb, acc, 0, 0, 0);
    }
#pragma unroll
    for (int ks = 0; ks < 8; ++ks){
      bf16x8 bb = *(const bf16x8*)&Ws[l16*520 + 256 + ks*32 + qd*8];
      acc = __builtin_amdgcn_mfma_f32_16x16x32_bf16(hf[ks], bb, acc, 0, 0, 0);
    }
    __syncthreads();
#pragma unroll
    for (int r = 0; r < 4; ++r)
      Gs[(w*16 + qd*4 + r)*17 + l16] = acc[r];
    __syncthreads();
    if (tid < 64){
      const int bl = tid;
      float hv[4];
#pragma unroll
      for (int u = 0; u < 4; ++u){
        const float gi = Gs[bl*17 + u*4 + 0] + bsh[u*4 + 0];
        const float gf = Gs[bl*17 + u*4 + 1] + bsh[u*4 + 1];
        const float gg = Gs[bl*17 + u*4 + 2] + bsh[u*4 + 2];
        const float go = Gs[bl*17 + u*4 + 3] + bsh[u*4 + 3];
        const float cn = sigm(gf)*c[u] + sigm(gi)*tanhf(gg);
        c[u] = cn;
        hv[u] = sigm(go)*tanhf(cn);
      }
      const int b2 = m_base + bl;
      const unsigned long long hq = pack4bf(hv[0],hv[1],hv[2],hv[3]);
      stc8(&hEnc[(((size_t)dir*2 + (size_t)((t+1)&1))*B + b2)*256 + ng*4], hq);
      *(unsigned long long*)&encOut[((size_t)b2*S + tt)*512 + dir*256 + ng*4] = hq;
    }
    bar_arr(myline);
  }
}

// ---------------------------------------------------------------------------
// proj = encOut @ W_src^T, precomputed once (step-invariant, as in reference).
// Output layout (B, 2, S, 256): d-half-major so decoder blocks load 128 KB
// contiguously. Grid 4096 = mtile(512) x ntile(8); 64x64 per block.
// ---------------------------------------------------------------------------
__global__ __launch_bounds__(256,2) void k_proj(
  const unsigned short* __restrict__ encOut,  // (B*S, 512)
  const unsigned short* __restrict__ WSP,     // swizzled B-frags (n=d, k=e)
  unsigned short* __restrict__ proj)          // (B, 2, S, 256)
{
  const int nb = blockIdx.x & 7;
  const int mt = blockIdx.x >> 3;
  const int tid = threadIdx.x;
  const int lane = tid & 63, w = tid >> 6;
  const int l16 = lane & 15, qd = lane >> 4;
  const int m0 = mt*64 + w*16;
  const unsigned short* Ap = encOut + ((size_t)m0 + l16)*512 + qd*8;
  bf16x8 av[16];
#pragma unroll
  for (int ks = 0; ks < 16; ++ks) av[ks] = *(const bf16x8*)(Ap + ks*32);
  for (int nn = 0; nn < 4; ++nn){
    const int qn = nb*4 + nn;          // 16-wide d group
    const unsigned short* Bq = WSP + (size_t)qn*16*512 + (size_t)lane*8;
    f32x4 acc = (f32x4){0.f,0.f,0.f,0.f};
#pragma unroll
    for (int ks = 0; ks < 16; ++ks){
      bf16x8 bb = *(const bf16x8*)(Bq + (size_t)ks*512);
      acc = __builtin_amdgcn_mfma_f32_16x16x32_bf16(av[ks], bb, acc, 0, 0, 0);
    }
    const int d = qn*16 + l16, dh = d >> 8, dl = d & 255;
#pragma unroll
    for (int r = 0; r < 4; ++r){
      const int m = m0 + qd*4 + r;
      const int bb2 = m >> 8, s = m & 255;
      proj[(((size_t)bb2*2 + dh)*256 + s)*256 + dl] = f2bf(acc[r]);
    }
  }
}

// ---------------------------------------------------------------------------
// Persistent decoder. Grid 256; block i owns (batch b=i>>1, d-half eh=i&1),
// holds proj[b, :, eh*256..+256) swizzled in LDS (128 KB) for all steps.
// Per step: [pre: h-part gates] -> Fwait(subset) -> feed-part gates -> barA
//   -> scores(h.proj) partial -> pair -> softmax -> ctx(encOut L2) -> barC
//   -> feed GEMM (h-part pre-waited) -> barF(own line).
// ---------------------------------------------------------------------------
__global__ __launch_bounds__(256,1) void k_decoder(
  const unsigned short* __restrict__ win,    // (T,B,64)
  const unsigned short* __restrict__ WDx,    // swizzled gates weights
  const float* __restrict__ bD,              // 2048 reordered
  const unsigned short* __restrict__ WCx,    // swizzled W_ctx
  const unsigned short* __restrict__ projq,  // (B,2,S,256) precomputed proj
  const unsigned short* __restrict__ encOut, // (B,S,512)
  const int* __restrict__ in_seq,
  const float* __restrict__ Wout, const float* __restrict__ bout,
  unsigned short* __restrict__ hdec,         // [2][B][512]
  unsigned short* __restrict__ feed,         // [B][512]
  unsigned short* __restrict__ ctxb,         // [B][512]
  float* __restrict__ scp,                   // [B][2][256] partial scores
  float* __restrict__ out_main, float* __restrict__ out_attn,
  unsigned* __restrict__ cnts)
{
  __shared__ __align__(16) unsigned short encS[65536];  // 128 KB resident proj tile
  __shared__ __align__(16) float scrf[1600];
  __shared__ float bsh[16];
  const int bid = blockIdx.x;
  const int b  = bid >> 1, eh = bid & 1;
  const int mg = bid & 1, ng = (bid >> 1) & 127;
  const int tid = threadIdx.x;
  const int lane = tid & 63, w = tid >> 6;
  const int l16 = lane & 15, qd = lane >> 4;
  const int m_base = mg*64;

  // ---- init: bias, mask, resident proj tile ----
  if (tid < 16) bsh[tid] = bD[ng*16 + tid];
  const int mymask = (in_seq[b*S + tid] == 0);
  {
    const unsigned short* Pq = projq + (((size_t)b*2 + eh)*256)*256;
    for (int i = 0; i < 32; ++i){
      const int s = i*8 + (tid>>5), cc = tid & 31;
      const uint4 v = *(const uint4*)&Pq[(size_t)s*256 + cc*8];
      *(uint4*)&encS[enc_idx(s, cc)] = v;
    }
  }
  float c[4] = {0.f,0.f,0.f,0.f};
  __syncthreads();

  for (int t = 0; t < T; ++t){
    // ---------------- phase A: gates + LSTM update ----------------
    const int row = m_base + w*16 + l16;
    const unsigned short* Aw = win  + ((size_t)t*B + row)*64 + qd*8;
    const unsigned short* Af = feed + (size_t)row*512 + qd*8;
    const unsigned short* Ah = hdec + ((size_t)(t&1)*B + row)*512 + qd*8;
    const unsigned short* Bp = WDx + (size_t)ng*34*512 + (size_t)lane*8;
    f32x4 acc = (f32x4){0.f,0.f,0.f,0.f};
    // pre-wait: h-part of gates (h_{t-1} visible since prev barA) — off chain
    {
      bf16x8 hv[16];
#pragma unroll
      for (int i = 0; i < 16; ++i) hv[i] = ldfrag_c(Ah + i*32);
#pragma unroll
      for (int ks = 0; ks < 16; ++ks){
        bf16x8 bb = *(const bf16x8*)(Bp + (size_t)(18+ks)*512);
        acc = __builtin_amdgcn_mfma_f32_16x16x32_bf16(hv[ks], bb, acc, 0, 0, 0);
      }
    }
    // prefetch feed-part weights + win frags (cached) before the wait
    bf16x8 bv0[18];
#pragma unroll
    for (int ks = 0; ks < 18; ++ks) bv0[ks] = *(const bf16x8*)(Bp + (size_t)ks*512);
    bf16x8 a0 = *(const bf16x8*)(Aw);
    bf16x8 a1 = *(const bf16x8*)(Aw + 32);
    // feed_{t-1} ready: even blocks consume rows 0..63 only (fm=0 subset);
    // odd blocks also run outproj on arbitrary row -> wait all 64 F lines.
    if (t){
      if (bid & 1) barw(cl(cnts, F_OFF), (unsigned)t, 63);
      else         barw(cl(cnts, F_OFF), (unsigned)t, 31);
    }
    {
      bf16x8 av[18];
      av[0] = a0; av[1] = a1;
#pragma unroll
      for (int i = 0; i < 16; ++i) av[2+i] = ldfrag_c(Af + i*32);
#pragma unroll
      for (int ks = 0; ks < 18; ++ks)
        acc = __builtin_amdgcn_mfma_f32_16x16x32_bf16(av[ks], bv0[ks], acc, 0, 0, 0);
    }
    __syncthreads();
#pragma unroll
    for (int r = 0; r < 4; ++r)
      scrf[(w*16 + qd*4 + r)*17 + l16] = acc[r];
    __syncthreads();
    if (tid < 64){
      float hv[4];
#pragma unroll
      for (int u = 0; u < 4; ++u){
        const float gi = scrf[tid*17 + u*4 + 0] + bsh[u*4 + 0];
        const float gf = scrf[tid*17 + u*4 + 1] + bsh[u*4 + 1];
        const float gg = scrf[tid*17 + u*4 + 2] + bsh[u*4 + 2];
        const float go = scrf[tid*17 + u*4 + 3] + bsh[u*4 + 3];
        const float cn = sigm(gf)*c[u] + sigm(gi)*tanhf(gg);
        c[u] = cn;
        hv[u] = sigm(go)*tanhf(cn);
      }
      stc8(&hdec[((size_t)((t+1)&1)*B + m_base + tid)*512 + ng*4],
           pack4bf(hv[0],hv[1],hv[2],hv[3]));
    }
    bar_arr(cl(cnts, A_OFF + (bid & 63)));

    // out-projection of feed_{t-1} (odd blocks; overlaps barA stragglers)
    if ((bid & 1) && t > 0){
      const int b2o = bid >> 1;
      const int d = tid >> 6, kk = lane;
      const unsigned short* fp = feed + (size_t)b2o*512 + kk*8;
      F16x8 u; u.q[0] = ldc8(fp); u.q[1] = ldc8(fp + 4);
      const float* wp = Wout + d*512 + kk*8;
      float p = 0.f;
#pragma unroll
      for (int j2 = 0; j2 < 8; ++j2) p += bf2f(u.s[j2]) * wp[j2];
#pragma unroll
      for (int off = 32; off > 0; off >>= 1) p += __shfl_down(p, off, 64);
      if (kk == 0){
        const float v = p + bout[d];
        out_main[((size_t)b2o*T + (t-1))*4 + d] = (d < 3) ? tanhf(v) : fmaxf(v, 0.f);
      }
    }

    // ---------------- attention (all blocks; d-half of batch b) ----------------
    barw(cl(cnts, A_OFF), (unsigned)(4u*(unsigned)(t+1)), 63);   // full h_t visible
    if (tid < 64){
      F16x8 uq; uq.q[0] = ldc8(hdec + ((size_t)((t+1)&1)*B + b)*512 + eh*256 + tid*4);
      scrf[tid*4+0] = bf2f(uq.s[0]); scrf[tid*4+1] = bf2f(uq.s[1]);
      scrf[tid*4+2] = bf2f(uq.s[2]); scrf[tid*4+3] = bf2f(uq.s[3]);
    }
    __syncthreads();
    float sc = 0.f;
#pragma unroll 8
    for (int cix = 0; cix < 32; ++cix){
      Ubf u8; u8.v = *(const bf16x8*)&encS[enc_idx(tid, cix)];
      float f0,f1,f2,f3,f4,f5,f6,f7;
      unp2(u8.u[0],f0,f1); unp2(u8.u[1],f2,f3); unp2(u8.u[2],f4,f5); unp2(u8.u[3],f6,f7);
      const float* qp = &scrf[cix*8];
      sc += f0*qp[0] + f1*qp[1] + f2*qp[2] + f3*qp[3]
          + f4*qp[4] + f5*qp[5] + f6*qp[6] + f7*qp[7];
    }
    stc4f(&scp[((size_t)b*2 + eh)*256 + tid], sc);
    pair_sync(cl(cnts, PAIR_OFF + b), (unsigned)(2u*(unsigned)(t+1)));
    float tot = sc + ldc4f(&scp[((size_t)b*2 + (1-eh))*256 + tid]);
    if (mymask) tot = -1e30f;
    // softmax over 256 s
    float mx = tot;
#pragma unroll
    for (int off = 32; off > 0; off >>= 1) mx = fmaxf(mx, __shfl_xor(mx, off, 64));
    if (lane == 0) scrf[512 + w] = mx;
    __syncthreads();
    mx = fmaxf(fmaxf(scrf[512], scrf[513]), fmaxf(scrf[514], scrf[515]));
    const float e = __expf(tot - mx);
    float l = e;
#pragma unroll
    for (int off = 32; off > 0; off >>= 1) l += __shfl_xor(l, off, 64);
    if (lane == 0) scrf[516 + w] = l;
    __syncthreads();
    l = scrf[516] + scrf[517] + scrf[518] + scrf[519];
    const float aw = e / l;
    scrf[256 + tid] = aw;
    if (eh == 0) __builtin_nontemporal_store(aw, &out_attn[((size_t)b*T + t)*S + tid]);
    __syncthreads();
    // ctx e-half from GLOBAL encOut (L2-resident): wave w covers 64 s rows
    {
      float a[8] = {0,0,0,0,0,0,0,0};
      const int cc = lane & 31, par = lane >> 5;
      const unsigned short* Ep = encOut + ((size_t)b*S)*512 + eh*256 + cc*8;
#pragma unroll 8
      for (int i2 = 0; i2 < 32; ++i2){
        const int srow = w*64 + i2*2 + par;
        const float wgt = scrf[256 + srow];
        Ubf u8; u8.v = *(const bf16x8*)(Ep + (size_t)srow*512);
        float f0,f1,f2,f3,f4,f5,f6,f7;
        unp2(u8.u[0],f0,f1); unp2(u8.u[1],f2,f3); unp2(u8.u[2],f4,f5); unp2(u8.u[3],f6,f7);
        a[0]+=wgt*f0; a[1]+=wgt*f1; a[2]+=wgt*f2; a[3]+=wgt*f3;
        a[4]+=wgt*f4; a[5]+=wgt*f5; a[6]+=wgt*f6; a[7]+=wgt*f7;
      }
#pragma unroll
      for (int j2 = 0; j2 < 8; ++j2) a[j2] += __shfl_xor(a[j2], 32, 64);
      if (par == 0){
#pragma unroll
        for (int j2 = 0; j2 < 8; ++j2) scrf[528 + w*256 + cc*8 + j2] = a[j2];
      }
    }
    __syncthreads();
    if (tid < 128){
      const int e2 = tid*2;
      const float s0 = scrf[528+e2]     + scrf[528+256+e2]     + scrf[528+512+e2]     + scrf[528+768+e2];
      const float s1 = scrf[528+e2+1]   + scrf[528+256+e2+1]   + scrf[528+512+e2+1]   + scrf[528+768+e2+1];
      stc4(&ctxb[(size_t)b*512 + eh*256 + e2],
           (unsigned)f2bf(s0) | ((unsigned)f2bf(s1) << 16));
    }
    bar_arr(cl(cnts, C_OFF + (bid & 63)));

    // ---------------- phase F: feed = tanh([h|ctx] @ W_ctx^T) (64 blocks) ----
    if ((bid & 3) == 3){
      const int fblk = bid >> 2, fm = fblk >> 5, fn = fblk & 31;
      const int frow = fm*64 + w*16 + l16;
      const unsigned short* Fh = hdec + ((size_t)((t+1)&1)*B + frow)*512 + qd*8;
      const unsigned short* Fc = ctxb + (size_t)frow*512 + qd*8;
      const unsigned short* Bf = WCx + (size_t)fn*32*512 + (size_t)lane*8;
      f32x4 fa = (f32x4){0.f,0.f,0.f,0.f};
      {   // h-part before ctx-wait (h ready since barA this step)
        bf16x8 av[16];
#pragma unroll
        for (int ks = 0; ks < 16; ++ks) av[ks] = ldfrag_c(Fh + ks*32);
#pragma unroll
        for (int ks = 0; ks < 16; ++ks){
          bf16x8 bb = *(const bf16x8*)(Bf + (size_t)ks*512);
          fa = __builtin_amdgcn_mfma_f32_16x16x32_bf16(av[ks], bb, fa, 0, 0, 0);
        }
      }
      bf16x8 bv2[16];
#pragma unroll
      for (int ks = 0; ks < 16; ++ks) bv2[ks] = *(const bf16x8*)(Bf + (size_t)(16+ks)*512);
      barw(cl(cnts, C_OFF), (unsigned)(4u*(unsigned)(t+1)), 63);
      {
        bf16x8 av[16];
#pragma unroll
        for (int ks = 0; ks < 16; ++ks) av[ks] = ldfrag_c(Fc + ks*32);
#pragma unroll
        for (int ks = 0; ks < 16; ++ks)
          fa = __builtin_amdgcn_mfma_f32_16x16x32_bf16(av[ks], bv2[ks], fa, 0, 0, 0);
      }
      __syncthreads();
#pragma unroll
      for (int r = 0; r < 4; ++r)
        scrf[(w*16 + qd*4 + r)*17 + l16] = tanhf(fa[r]);
      __syncthreads();
      if (tid < 64){
        const int fb = fm*64 + tid;
#pragma unroll
        for (int u = 0; u < 4; ++u)
          stc8(&feed[(size_t)fb*512 + fn*16 + u*4],
               pack4bf(scrf[tid*17+u*4+0], scrf[tid*17+u*4+1],
                       scrf[tid*17+u*4+2], scrf[tid*17+u*4+3]));
      }
      bar_arr(cl(cnts, F_OFF + (bid >> 2)));   // own line: 1 arrival/step
    }
  }
  // final out-projection (feed_255)
  if (bid & 1){
    barw(cl(cnts, F_OFF), 256u, 63);
    const int b2o = bid >> 1;
    const int d = tid >> 6, kk = lane;
    const unsigned short* fp = feed + (size_t)b2o*512 + kk*8;
    F16x8 u; u.q[0] = ldc8(fp); u.q[1] = ldc8(fp + 4);
    const float* wp = Wout + d*512 + kk*8;
    float p = 0.f;
#pragma unroll
    for (int j2 = 0; j2 < 8; ++j2) p += bf2f(u.s[j2]) * wp[j2];
#pragma unroll
    for (int off = 32; off > 0; off >>= 1) p += __shfl_down(p, off, 64);
    if (kk == 0){
      const float v = p + bout[d];
      out_main[((size_t)b2o*T + 255)*4 + d] = (d < 3) ? tanhf(v) : fmaxf(v, 0.f);
    }
  }
}

// ---------------- setup / builder kernels ----------------
__global__ __launch_bounds__(256) void k_build_encw(
  const float* __restrict__ WihF, const float* __restrict__ WhhF,
  const float* __restrict__ WihB, const float* __restrict__ WhhB,
  unsigned short* WF, unsigned short* WB)
{
  const int idx = blockIdx.x*256 + threadIdx.x;     // 2*1024*512
  const int dir = idx >> 19;
  const int i2 = idx & 524287;
  const int row = i2 >> 9, col = i2 & 511;
  const int j = row >> 2, g = row & 3;
  const int orig = g*256 + j;
  const float* Wih = dir ? WihB : WihF;
  const float* Whh = dir ? WhhB : WhhF;
  const float v = (col < 256) ? Wih[orig*256 + col] : Whh[orig*256 + (col-256)];
  (dir ? WB : WF)[i2] = f2bf(v);
}

// gates weights: reorder rows (j*4+g), pad cols to 1088, swizzle to frag order
__global__ __launch_bounds__(256) void k_build_decw(
  const float* __restrict__ Wih, const float* __restrict__ Whh, unsigned short* WDx)
{
  const int idx = blockIdx.x*256 + threadIdx.x;
  if (idx >= 2048*1088) return;
  const int row = idx / 1088, col = idx - row*1088;
  const int j = row >> 2, g = row & 3;
  const int orig = g*512 + j;
  float v;
  if (col < 16)        v = Wih[orig*528 + col];          // w_t part
  else if (col < 64)   v = 0.f;                          // pad
  else if (col < 576)  v = Wih[orig*528 + (col - 48)];   // feed part
  else                 v = Whh[orig*512 + (col - 576)];  // h part
  const int ng = row >> 4, l16 = row & 15;
  const int ks = col >> 5, qdd = (col >> 3) & 3, jj = col & 7;
  WDx[(((size_t)ng*34 + ks)*64 + qdd*16 + l16)*8 + jj] = f2bf(v);
}

__global__ __launch_bounds__(256) void k_build_wcx(
  const float* __restrict__ Wctx, unsigned short* WCx)
{
  const int idx = blockIdx.x*256 + threadIdx.x;     // 512*1024
  const int n = idx >> 10, k = idx & 1023;
  const int fn = n >> 4, l16 = n & 15;
  const int ks = k >> 5, qdd = (k >> 3) & 3, jj = k & 7;
  WCx[(((size_t)fn*32 + ks)*64 + qdd*16 + l16)*8 + jj] = f2bf(Wctx[(size_t)n*1024 + k]);
}

// W_src in B-frag order for proj GEMM: n = d (512), k = e (512)
__global__ __launch_bounds__(256) void k_build_wsp(
  const float* __restrict__ Wsrc, unsigned short* WSP)
{
  const int idx = blockIdx.x*256 + threadIdx.x;     // 512*512
  const int d = idx >> 9, e = idx & 511;
  const int qn = d >> 4, l16 = d & 15;
  const int ks = e >> 5, qdd = (e >> 3) & 3, jj = e & 7;
  WSP[(((size_t)qn*16 + ks)*64 + qdd*16 + l16)*8 + jj] = f2bf(Wsrc[(size_t)d*512 + e]);
}

__global__ __launch_bounds__(256) void k_build_bias(
  const float* __restrict__ ebF, const float* __restrict__ ebB,
  const float* __restrict__ dB, float* bF, float* bB, float* bD)
{
  const int idx = blockIdx.x*256 + threadIdx.x;     // 4096
  if (idx < 1024) bF[idx] = ebF[(idx&3)*256 + (idx>>2)];
  else if (idx < 2048){ const int i = idx-1024; bB[i] = ebB[(i&3)*256 + (i>>2)]; }
  else { const int i = idx-2048; bD[i] = dB[(i&3)*512 + (i>>2)]; }
}

__global__ __launch_bounds__(256) void k_embed(
  const int* __restrict__ in_seq, const float* __restrict__ table, unsigned short* emb)
{
  const int idx = blockIdx.x*256 + threadIdx.x;     // S*B*256, layout (S,B,E)
  const int e = idx & 255, b = (idx >> 8) & 127, s = idx >> 15;
  const int tok = in_seq[b*S + s];
  emb[idx] = f2bf(table[(size_t)tok*256 + e]);
}

__global__ __launch_bounds__(256) void k_win(
  const float* __restrict__ tgt, unsigned short* win)
{
  const int idx = blockIdx.x*256 + threadIdx.x;     // T*B*64, layout (T,B,64)
  const int c = idx & 63, b = (idx >> 6) & 127, t = idx >> 13;
  float v = 0.f;
  if (c < 16){
    const int k = c >> 2, jj = c & 3;
    const int ts = t + k - 4;
    if (ts >= 0) v = tgt[((size_t)b*T + ts)*4 + jj];
  }
  win[idx] = f2bf(v);
}

// ---------------------------------------------------------------------------
extern "C" void kernel_launch(void* const* d_in, const int* in_sizes, int n_in,
                              void* d_out, int out_size, void* d_ws, size_t ws_size,
                              hipStream_t stream)
{
  const int*   in_seq    = (const int*)d_in[0];
  const float* tgt       = (const float*)d_in[1];
  // d_in[2] = lengths (unused by reference)
  const float* embedding = (const float*)d_in[3];
  const float* eWihF = (const float*)d_in[4];
  const float* eWhhF = (const float*)d_in[5];
  const float* ebF   = (const float*)d_in[6];
  const float* eWihB = (const float*)d_in[7];
  const float* eWhhB = (const float*)d_in[8];
  const float* ebB   = (const float*)d_in[9];
  const float* dWih  = (const float*)d_in[10];
  const float* dWhh  = (const float*)d_in[11];
  const float* dB    = (const float*)d_in[12];
  const float* Wsrc  = (const float*)d_in[13];
  const float* Wctx  = (const float*)d_in[14];
  const float* Wout  = (const float*)d_in[15];
  const float* bout  = (const float*)d_in[16];

  char* ws = (char*)d_ws;
  size_t off = 0;
  auto al = [&](size_t bytes)->char*{
    char* p = ws + off; off += (bytes + 255) & ~(size_t)255; return p; };

  // --- state region (zeroed every launch with one memset) ---
  char* stateBase = ws;
  unsigned short* hEnc = (unsigned short*)al(262144);  // [2][2][128][256]
  unsigned short* hdec = (unsigned short*)al(262144);  // [2][128][512]
  unsigned short* feed = (unsigned short*)al(131072);  // [128][512]
  unsigned short* ctxb = (unsigned short*)al(131072);  // [128][512]
  unsigned*       cnts = (unsigned*)al(45056);         // 352 counter lines
  const size_t stateBytes = off;

  // --- persistent-per-launch scratch (fully rewritten each launch) ---
  unsigned short* emb    = (unsigned short*)al(16777216);  // (S,B,256) bf16
  unsigned short* win    = (unsigned short*)al(4194304);   // (T,B,64) bf16
  unsigned short* encOut = (unsigned short*)al(33554432);  // (B,S,512) bf16
  unsigned short* proj   = (unsigned short*)al(33554432);  // (B,2,S,256) bf16
  unsigned short* WF     = (unsigned short*)al(1048576);   // 1024x512
  unsigned short* WB     = (unsigned short*)al(1048576);
  unsigned short* WDx    = (unsigned short*)al(4456448);   // swizzled 2048x1088
  unsigned short* WCx    = (unsigned short*)al(1048576);   // swizzled 512x1024
  unsigned short* WSP    = (unsigned short*)al(524288);    // swizzled 512x512 (proj B)
  float*          scp    = (float*)al(262144);             // [128][2][256]
  float* bFr = (float*)al(4096);
  float* bBr = (float*)al(4096);
  float* bDr = (float*)al(8192);
  (void)ws_size; (void)in_sizes; (void)n_in; (void)out_size;

  float* out_main = (float*)d_out;
  float* out_attn = out_main + (size_t)B*T*DOF;

  const dim3 blk(256);
  k_build_encw <<<4096,  blk, 0, stream>>>(eWihF, eWhhF, eWihB, eWhhB, WF, WB);
  k_build_decw <<<8704,  blk, 0, stream>>>(dWih, dWhh, WDx);
  k_build_wcx  <<<2048,  blk, 0, stream>>>(Wctx, WCx);
  k_build_wsp  <<<1024,  blk, 0, stream>>>(Wsrc, WSP);
  k_build_bias <<<16,    blk, 0, stream>>>(ebF, ebB, dB, bFr, bBr, bDr);
  k_embed      <<<32768, blk, 0, stream>>>(in_seq, embedding, emb);
  k_win        <<<8192,  blk, 0, stream>>>(tgt, win);
  hipMemsetAsync(stateBase, 0, stateBytes, stream);

  // persistent encoder: 256 steps internally
  k_encoder<<<256, blk, 0, stream>>>(emb, WF, WB, bFr, bBr, hEnc, encOut,
                                     cnts + (size_t)ENC_OFF*CLINE);

  // one-shot proj GEMM (step-invariant attention projection)
  k_proj<<<4096, blk, 0, stream>>>(encOut, WSP, proj);

  // persistent decoder: 256 steps internally (proj LDS-resident, spread barriers)
  k_decoder<<<256, blk, 0, stream>>>(win, WDx, bDr, WCx, proj, encOut, in_seq,
                                     Wout, bout, hdec, feed, ctxb, scp,
                                     out_main, out_attn, cnts);
}